// Round 4
// baseline (184.214 us; speedup 1.0000x reference)
//
#include <hip/hip_runtime.h>
#include <hip/hip_bf16.h>

// Linear layer: out[M,N] = x[M,K] @ W[N,K]^T + b[N], fp32 in/out.
// M=32768, N=512, K=512. bf16 MFMA, fp32 accumulate.
// R5: dbuf LDS (1 barrier/iter), dist-2 A prefetch, XCD swizzle. 53 us.
// R6: 32 KB LDS + chunk-XOR swizzle (conflicts 4.2M -> 0) but (256,4)
//     VGPR squeeze -> spills (FETCH+WRITE +45MB), 79 us.
// R7: (256,3): spills gone, 56 us. Counters across R5/R6/R7 all show
//     effective BW pinned at ~2.0 TB/s => Little's-law latency ceiling,
//     caused by __syncthreads() draining vmcnt(0) at all 16 barriers
//     (prefetch never spans a barrier; waves stall phase-aligned).
// R8: raw barrier "s_waitcnt lgkmcnt(0); s_barrier" (vmem stays in flight
//     across barriers — LDS ordering is all the barrier must guarantee;
//     global loads only write private VGPRs). W prefetch made dist-2 like
//     A. sched_barrier(0) pins load-issue before the compute phase.
//     (Bench attempt failed on container infra, no counters; resubmitted
//     with the barrier expressed as the learn_hip-verified builtin idiom.)

#define M_DIM 32768
#define N_DIM 512
#define K_DIM 512
#define BK 32
#define LDA 32   // bf16 elems per row (64 B); swizzled, no pad needed

typedef __bf16 bf16x8 __attribute__((ext_vector_type(8)));
typedef __bf16 bf16x4 __attribute__((ext_vector_type(4)));
typedef float floatx4 __attribute__((ext_vector_type(4)));

__global__ __launch_bounds__(256, 3) void linear_dbuf(
    const float* __restrict__ A,    // [M, K]
    const float* __restrict__ W,    // [N, K]
    const float* __restrict__ bias, // [N]
    float* __restrict__ C)          // [M, N]
{
    // 2 buffers x 2 arrays x 128 rows x 32 bf16 x 2 B = 32 KiB total.
    __shared__ __bf16 sA[2][128 * LDA];
    __shared__ __bf16 sW[2][128 * LDA];

    const int t = threadIdx.x;
    const int bid = blockIdx.x;
    // XCD swizzle: 4 n-tiles of an m-tile land on one XCD adjacent slots.
    const int nT = (bid >> 3) & 3;
    const int mT = (bid & 7) | ((bid >> 5) << 3);
    const int mBlock = mT * 128;
    const int nBlock = nT * 128;

    const int wave = t >> 6;
    const int lane = t & 63;
    const int mW = (wave >> 1) * 64;
    const int nW = (wave & 1) * 64;
    const int kh = lane >> 4;
    const int l16 = lane & 15;

    floatx4 acc[4][4];
#pragma unroll
    for (int i = 0; i < 4; ++i)
#pragma unroll
        for (int j = 0; j < 4; ++j)
            acc[i][j] = (floatx4)0.f;

    // Staging map: thread t covers rows sRow+{0,32,64,96}, 4 floats at col
    // sCol. Coalesced 128B per 8-lane row-group.
    const int sRow = t >> 3;
    const int sCol = (t & 7) * 4;
    // Swizzled elem offset within a row: each row = 4 chunks of 8 bf16 (16 B);
    // chunk' = chunk ^ ((row>>1)&3). (row>>1)&3 is invariant under row += 32,
    // so one constant serves all 4 staged rows. sCol&4 selects the 8 B half.
    const int wOff = (((sCol >> 3) ^ ((sRow >> 1) & 3)) << 3) + (sCol & 4);
    // Read side: fragment chunk kh of row (.. + l16); (row>>1)&3 == (l16>>1)&3
    // since mW, mi*16, nW, ni*16 are all multiples of 16.
    const int rk = (kh ^ ((l16 >> 1) & 3)) << 3;

    const float* aBase = A + (size_t)(mBlock + sRow) * K_DIM + sCol;
    const float* wBase = W + (size_t)(nBlock + sRow) * K_DIM + sCol;

    // Register prefetch, distance 2 for BOTH A and W: set [cur] is consumed
    // by STEP(cur) staging and re-issued for kt+2*BK right after the barrier.
    floatx4 pa[2][4], pw[2][4];
#pragma unroll
    for (int i = 0; i < 4; ++i) {
        pa[0][i] = *(const floatx4*)(aBase + (size_t)i * 32 * K_DIM);
        pa[1][i] = *(const floatx4*)(aBase + 32 + (size_t)i * 32 * K_DIM);
        pw[0][i] = *(const floatx4*)(wBase + (size_t)i * 32 * K_DIM);
        pw[1][i] = *(const floatx4*)(wBase + 32 + (size_t)i * 32 * K_DIM);
    }

#define STEP(cur, kt)                                                         \
    {                                                                         \
        _Pragma("unroll") for (int i = 0; i < 4; ++i) {                       \
            const int row = sRow + i * 32;                                    \
            bf16x4 ab, wb;                                                    \
            _Pragma("unroll") for (int j = 0; j < 4; ++j) {                   \
                ab[j] = (__bf16)pa[cur][i][j];                                \
                wb[j] = (__bf16)pw[cur][i][j];                                \
            }                                                                 \
            *(bf16x4*)&sA[cur][row * LDA + wOff] = ab;                        \
            *(bf16x4*)&sW[cur][row * LDA + wOff] = wb;                        \
        }                                                                     \
        /* Drain LDS (lgkm) ONLY, then barrier — global loads stay in    */   \
        /* flight across it (they write private VGPRs only; the double   */   \
        /* buffer makes one barrier/STEP sufficient).                    */   \
        asm volatile("s_waitcnt lgkmcnt(0)" ::: "memory");                    \
        __builtin_amdgcn_s_barrier();                                         \
        if ((kt) + 2 * BK < K_DIM) {                                          \
            _Pragma("unroll") for (int i = 0; i < 4; ++i) {                   \
                pa[cur][i] = *(const floatx4*)(aBase + (kt) + 2 * BK +        \
                                               (size_t)i * 32 * K_DIM);       \
                pw[cur][i] = *(const floatx4*)(wBase + (kt) + 2 * BK +        \
                                               (size_t)i * 32 * K_DIM);       \
            }                                                                 \
        }                                                                     \
        /* Pin load-issue before the compute phase (no sinking to use). */    \
        __builtin_amdgcn_sched_barrier(0);                                    \
        bf16x8 aF[4], wF[4];                                                  \
        _Pragma("unroll") for (int mi = 0; mi < 4; ++mi)                      \
            aF[mi] = *(const bf16x8*)&sA[cur][(mW + mi * 16 + l16) * LDA +    \
                                             rk];                             \
        _Pragma("unroll") for (int ni = 0; ni < 4; ++ni)                      \
            wF[ni] = *(const bf16x8*)&sW[cur][(nW + ni * 16 + l16) * LDA +    \
                                             rk];                             \
        _Pragma("unroll") for (int mi = 0; mi < 4; ++mi)                      \
            _Pragma("unroll") for (int ni = 0; ni < 4; ++ni)                  \
                acc[mi][ni] = __builtin_amdgcn_mfma_f32_16x16x32_bf16(        \
                    aF[mi], wF[ni], acc[mi][ni], 0, 0, 0);                    \
    }

    for (int it8 = 0; it8 < 8; ++it8) {
        const int kt = it8 * 2 * BK;
        STEP(0, kt);
        STEP(1, kt + BK);
    }
#undef STEP

    // Epilogue: D mapping col = lane&15, row = (lane>>4)*4 + reg (verified).
#pragma unroll
    for (int ni = 0; ni < 4; ++ni) {
        const int gcol = nBlock + nW + ni * 16 + l16;
        const float bv = bias[gcol];
#pragma unroll
        for (int mi = 0; mi < 4; ++mi) {
            const int rowBase = mBlock + mW + mi * 16 + kh * 4;
#pragma unroll
            for (int r = 0; r < 4; ++r)
                C[(size_t)(rowBase + r) * N_DIM + gcol] = acc[mi][ni][r] + bv;
        }
    }
}

extern "C" void kernel_launch(void* const* d_in, const int* in_sizes, int n_in,
                              void* d_out, int out_size, void* d_ws, size_t ws_size,
                              hipStream_t stream) {
    const float* x = (const float*)d_in[0];
    const float* w = (const float*)d_in[1];
    const float* b = (const float*)d_in[2];
    float* out = (float*)d_out;

    dim3 grid((M_DIM / 128) * (N_DIM / 128));  // 1024 blocks, 1D for swizzle
    dim3 block(256);
    linear_dbuf<<<grid, block, 0, stream>>>(x, w, b, out);
}

// Round 5
// 138.003 us; speedup vs baseline: 1.3349x; 1.3349x over previous
//
#include <hip/hip_runtime.h>
#include <hip/hip_bf16.h>

// Linear layer: out[M,N] = x[M,K] @ W[N,K]^T + b[N], fp32 in/out.
// M=32768, N=512, K=512. bf16 MFMA, fp32 accumulate.
// R5: dbuf LDS (1 barrier/iter), dist-2 A prefetch, XCD swizzle. 53 us.
// R6: 32 KB LDS + chunk-XOR swizzle (conflicts 4.2M -> 0) but (256,4)
//     VGPR squeeze -> spills (FETCH+WRITE +45MB), 79 us.
// R7: (256,3): spills gone, 56 us, VGPR 76. BW pinned ~2.0 TB/s in all
//     clean rounds => latency ceiling; suspect __syncthreads()'s implicit
//     s_waitcnt vmcnt(0) drain at each of the 16 barriers.
// R8: lgkm-only barrier + pw dist-2 + sched_barrier(0): live state ~180
//     VGPR > 168 cap -> scratch (WRITE 66->108 MB), 100 us. Theory never
//     tested cleanly: three variables changed, register squeeze dominated.
// R9 (this): EXACTLY R7 + ONE delta: __syncthreads() replaced by the
//     HW-verified T4 idiom  asm("s_waitcnt lgkmcnt(0)"); s_barrier();
//     Global prefetch loads stay in flight across barriers (they only
//     write private VGPRs; the barrier only needs to order LDS). W stays
//     dist-1, A dist-2, no sched_barrier -> pressure back at R7 levels.
//     Gate: WRITE must stay ~66 MB (no scratch), else round is void.

#define M_DIM 32768
#define N_DIM 512
#define K_DIM 512
#define BK 32
#define LDA 32   // bf16 elems per row (64 B); swizzled, no pad needed

typedef __bf16 bf16x8 __attribute__((ext_vector_type(8)));
typedef __bf16 bf16x4 __attribute__((ext_vector_type(4)));
typedef float floatx4 __attribute__((ext_vector_type(4)));

__global__ __launch_bounds__(256, 3) void linear_dbuf(
    const float* __restrict__ A,    // [M, K]
    const float* __restrict__ W,    // [N, K]
    const float* __restrict__ bias, // [N]
    float* __restrict__ C)          // [M, N]
{
    // 2 buffers x 2 arrays x 128 rows x 32 bf16 x 2 B = 32 KiB total.
    __shared__ __bf16 sA[2][128 * LDA];
    __shared__ __bf16 sW[2][128 * LDA];

    const int t = threadIdx.x;
    const int bid = blockIdx.x;
    // XCD swizzle: 4 n-tiles of an m-tile land on one XCD adjacent slots.
    const int nT = (bid >> 3) & 3;
    const int mT = (bid & 7) | ((bid >> 5) << 3);
    const int mBlock = mT * 128;
    const int nBlock = nT * 128;

    const int wave = t >> 6;
    const int lane = t & 63;
    const int mW = (wave >> 1) * 64;
    const int nW = (wave & 1) * 64;
    const int kh = lane >> 4;
    const int l16 = lane & 15;

    floatx4 acc[4][4];
#pragma unroll
    for (int i = 0; i < 4; ++i)
#pragma unroll
        for (int j = 0; j < 4; ++j)
            acc[i][j] = (floatx4)0.f;

    // Staging map: thread t covers rows sRow+{0,32,64,96}, 4 floats at col
    // sCol. Coalesced 128B per 8-lane row-group.
    const int sRow = t >> 3;
    const int sCol = (t & 7) * 4;
    // Swizzled elem offset within a row: each row = 4 chunks of 8 bf16 (16 B);
    // chunk' = chunk ^ ((row>>1)&3). (row>>1)&3 is invariant under row += 32,
    // so one constant serves all 4 staged rows. sCol&4 selects the 8 B half.
    const int wOff = (((sCol >> 3) ^ ((sRow >> 1) & 3)) << 3) + (sCol & 4);
    // Read side: fragment chunk kh of row (.. + l16); (row>>1)&3 == (l16>>1)&3
    // since mW, mi*16, nW, ni*16 are all multiples of 16.
    const int rk = (kh ^ ((l16 >> 1) & 3)) << 3;

    const float* aBase = A + (size_t)(mBlock + sRow) * K_DIM + sCol;
    const float* wBase = W + (size_t)(nBlock + sRow) * K_DIM + sCol;

    // Register prefetch: A has two sets (distance 2), W one set (distance 1).
    floatx4 pa[2][4], pw[4];
#pragma unroll
    for (int i = 0; i < 4; ++i) {
        pa[0][i] = *(const floatx4*)(aBase + (size_t)i * 32 * K_DIM);
        pa[1][i] = *(const floatx4*)(aBase + 32 + (size_t)i * 32 * K_DIM);
        pw[i]    = *(const floatx4*)(wBase + (size_t)i * 32 * K_DIM);
    }

#define STEP(cur, kt)                                                         \
    {                                                                         \
        _Pragma("unroll") for (int i = 0; i < 4; ++i) {                       \
            const int row = sRow + i * 32;                                    \
            bf16x4 ab, wb;                                                    \
            _Pragma("unroll") for (int j = 0; j < 4; ++j) {                   \
                ab[j] = (__bf16)pa[cur][i][j];                                \
                wb[j] = (__bf16)pw[i][j];                                     \
            }                                                                 \
            *(bf16x4*)&sA[cur][row * LDA + wOff] = ab;                        \
            *(bf16x4*)&sW[cur][row * LDA + wOff] = wb;                        \
        }                                                                     \
        /* T4 barrier: drain LDS (lgkm) ONLY. Global prefetch loads stay */   \
        /* in flight across the barrier; compiler inserts counted vmcnt  */   \
        /* at their use sites (next STEP's cvt).                         */   \
        asm volatile("s_waitcnt lgkmcnt(0)" ::: "memory");                    \
        __builtin_amdgcn_s_barrier();                                         \
        if ((kt) + BK < K_DIM) /* W for next iter: issue FIRST */             \
            _Pragma("unroll") for (int i = 0; i < 4; ++i)                     \
                pw[i] = *(const floatx4*)(wBase + (kt) + BK +                 \
                                          (size_t)i * 32 * K_DIM);            \
        if ((kt) + 2 * BK < K_DIM) /* A for iter+2 into the freed set */      \
            _Pragma("unroll") for (int i = 0; i < 4; ++i)                     \
                pa[cur][i] = *(const floatx4*)(aBase + (kt) + 2 * BK +        \
                                               (size_t)i * 32 * K_DIM);       \
        bf16x8 aF[4], wF[4];                                                  \
        _Pragma("unroll") for (int mi = 0; mi < 4; ++mi)                      \
            aF[mi] = *(const bf16x8*)&sA[cur][(mW + mi * 16 + l16) * LDA +    \
                                             rk];                             \
        _Pragma("unroll") for (int ni = 0; ni < 4; ++ni)                      \
            wF[ni] = *(const bf16x8*)&sW[cur][(nW + ni * 16 + l16) * LDA +    \
                                             rk];                             \
        _Pragma("unroll") for (int mi = 0; mi < 4; ++mi)                      \
            _Pragma("unroll") for (int ni = 0; ni < 4; ++ni)                  \
                acc[mi][ni] = __builtin_amdgcn_mfma_f32_16x16x32_bf16(        \
                    aF[mi], wF[ni], acc[mi][ni], 0, 0, 0);                    \
    }

    for (int it8 = 0; it8 < 8; ++it8) {
        const int kt = it8 * 2 * BK;
        STEP(0, kt);
        STEP(1, kt + BK);
    }
#undef STEP

    // Epilogue: D mapping col = lane&15, row = (lane>>4)*4 + reg (verified).
#pragma unroll
    for (int ni = 0; ni < 4; ++ni) {
        const int gcol = nBlock + nW + ni * 16 + l16;
        const float bv = bias[gcol];
#pragma unroll
        for (int mi = 0; mi < 4; ++mi) {
            const int rowBase = mBlock + mW + mi * 16 + kh * 4;
#pragma unroll
            for (int r = 0; r < 4; ++r)
                C[(size_t)(rowBase + r) * N_DIM + gcol] = acc[mi][ni][r] + bv;
        }
    }
}

extern "C" void kernel_launch(void* const* d_in, const int* in_sizes, int n_in,
                              void* d_out, int out_size, void* d_ws, size_t ws_size,
                              hipStream_t stream) {
    const float* x = (const float*)d_in[0];
    const float* w = (const float*)d_in[1];
    const float* b = (const float*)d_in[2];
    float* out = (float*)d_out;

    dim3 grid((M_DIM / 128) * (N_DIM / 128));  // 1024 blocks, 1D for swizzle
    dim3 block(256);
    linear_dbuf<<<grid, block, 0, stream>>>(x, w, b, out);
}